// Round 1
// 6214.831 us; speedup vs baseline: 1.1183x; 1.1183x over previous
//
#include <hip/hip_runtime.h>
#include <hip/hip_bf16.h>

typedef __bf16 bf16x8 __attribute__((ext_vector_type(8)));
typedef float f32x4 __attribute__((ext_vector_type(4)));
typedef unsigned long long u64;

#define MFMA16(a, b, c) __builtin_amdgcn_mfma_f32_16x16x32_bf16((a), (b), (c), 0, 0, 0)

#define HN_OFF 8388608ull   // 32*512*512
#define CN_OFF 8421376ull   // HN_OFF + 2*32*512

__device__ __forceinline__ float sigf(float x) { return 1.0f / (1.0f + __expf(-x)); }
__device__ __forceinline__ float b2f(unsigned short u) {
    union { unsigned u; float f; } c; c.u = ((unsigned)u) << 16; return c.f;
}
__device__ __forceinline__ unsigned short f2u(float f) {
    __hip_bfloat16 h = __float2bfloat16(f); return *(unsigned short*)&h;
}

// agent-scope (cross-XCD coherent) accessors
__device__ __forceinline__ u64 gload8(const void* p) {
    return __hip_atomic_load((const u64*)p, __ATOMIC_RELAXED, __HIP_MEMORY_SCOPE_AGENT);
}
__device__ __forceinline__ void gstore4(void* p, unsigned v) {
    __hip_atomic_store((unsigned*)p, v, __ATOMIC_RELAXED, __HIP_MEMORY_SCOPE_AGENT);
}

// split fp32 -> (hi, lo) bf16 pair
__device__ __forceinline__ void split8(const float* p, bf16x8& hi, bf16x8& lo) {
    union { __hip_bfloat16 h[8]; bf16x8 v; } uh, ul;
    #pragma unroll
    for (int i = 0; i < 8; ++i) {
        __hip_bfloat16 e = __float2bfloat16(p[i]);
        uh.h[i] = e;
        ul.h[i] = __float2bfloat16(p[i] - __bfloat162float(e));
    }
    hi = uh.v; lo = ul.v;
}

// ---------------- dtype probe (wave-parallel): 1 = fp32 inputs, 0 = bf16 ----------------
__global__ __launch_bounds__(256) void lstm_detect(
    const unsigned* __restrict__ Wq, unsigned* __restrict__ dflag,
    unsigned* __restrict__ flags)
{
    for (int j = threadIdx.x; j < 1024; j += 256) flags[j] = 0;
    if (threadIdx.x < 64) {
        int lane = threadIdx.x;
        int bad = 0;
        #pragma unroll
        for (int i = 0; i < 4; ++i) {
            unsigned u = Wq[(size_t)(lane + i * 64) * 4093];
            float v = b2f((unsigned short)(u & 0xFFFFu));
            if (!(v == v) || fabsf(v) > 100.0f) ++bad;
        }
        #pragma unroll
        for (int off = 32; off; off >>= 1) bad += __shfl_down(bad, off, 64);
        if (lane == 0) *dflag = (bad > 32) ? 1u : 0u;
    }
}

// ---------------- init: inputs -> hi/lo state, fp32 c ----------------
// h0 ring slot 0 gets h0[-1]; h1 parity 0 gets h1[-1].
__global__ __launch_bounds__(256) void lstm_init(
    const void* __restrict__ h0v, const void* __restrict__ c0v,
    __hip_bfloat16* __restrict__ h0hi, __hip_bfloat16* __restrict__ h0lo,
    __hip_bfloat16* __restrict__ h1hi, __hip_bfloat16* __restrict__ h1lo,
    float* __restrict__ cws, const unsigned* __restrict__ dflag)
{
    const bool f32 = (*dflag != 0);
    int i = blockIdx.x * 256 + threadIdx.x;   // i = b*512 + n
    int b = i >> 9, n = i & 511;
    float f0, f1, g0, g1;
    if (f32) {
        const float* h = (const float*)h0v; const float* c = (const float*)c0v;
        f0 = h[(b * 2 + 0) * 512 + n];  f1 = h[(b * 2 + 1) * 512 + n];
        g0 = c[(b * 2 + 0) * 512 + n];  g1 = c[(b * 2 + 1) * 512 + n];
    } else {
        const unsigned short* h = (const unsigned short*)h0v;
        const unsigned short* c = (const unsigned short*)c0v;
        f0 = b2f(h[(b * 2 + 0) * 512 + n]);  f1 = b2f(h[(b * 2 + 1) * 512 + n]);
        g0 = b2f(c[(b * 2 + 0) * 512 + n]);  g1 = b2f(c[(b * 2 + 1) * 512 + n]);
    }
    __hip_bfloat16 e0 = __float2bfloat16(f0), e1 = __float2bfloat16(f1);
    h0hi[i] = e0; h0lo[i] = __float2bfloat16(f0 - __bfloat162float(e0));
    h1hi[i] = e1; h1lo[i] = __float2bfloat16(f1 - __bfloat162float(e1));
    cws[i] = g0;  cws[16384 + i] = g1;
}

// ---------------- persistent scan: 64 WGs (even=layer0, odd=layer1) ----------------
// LDS tiles: A-hi @0, A-lo @32K, R-hi @64K, R-lo @96K; gbuf stride 17.
// h0 = 4-slot ring (written slot (k+1)&3 at p0 step k); h1 = 2-parity.
// Decoupled flags: p0 waits even>=k, odd>=k-2; p1 waits even>=k then odd>=k.
__global__ __launch_bounds__(256, 1) void lstm_seq(
    const void* __restrict__ xv,
    const void* __restrict__ Wxv, const void* __restrict__ bxv,
    const void* __restrict__ Whv, const void* __restrict__ bhv,
    __hip_bfloat16* __restrict__ h0hi, __hip_bfloat16* __restrict__ h0lo,
    __hip_bfloat16* __restrict__ h1hi, __hip_bfloat16* __restrict__ h1lo,
    const float* __restrict__ cws, unsigned* __restrict__ flags,
    const unsigned* __restrict__ dflag, void* __restrict__ outv)
{
    const bool f32 = (*dflag != 0);
    const int p  = blockIdx.x & 1;
    const int wt = blockIdx.x >> 1;
    const int tid = threadIdx.x;
    const int q = tid >> 6, lane = tid & 63;
    const int n16 = lane & 15, quad = lane >> 4;
    const int colg = q * 512 + wt * 16 + n16;

    __shared__ __align__(16) char smem[131072];
    __shared__ float gbuf[2176];              // [4 gates][32 rows] stride 17

    float* outf = (float*)outv;
    __hip_bfloat16* outh = (__hip_bfloat16*)outv;

    // --- weights -> hi(/lo) bf16 fragments, register-resident for all 512 steps ---
    bf16x8 wa[16], wal[16], wr[16], wrl[16];
    if (f32) {
        const float* WA = (const float*)Wxv + ((size_t)(p * 2048 + colg)) * 512;
        const float* WR = (const float*)Whv + ((size_t)(p * 2048 + colg)) * 512;
        #pragma unroll
        for (int kk = 0; kk < 16; ++kk) {
            split8(WA + kk * 32 + quad * 8, wa[kk], wal[kk]);
            split8(WR + kk * 32 + quad * 8, wr[kk], wrl[kk]);
        }
    } else {
        const unsigned short* WA = (const unsigned short*)Wxv + ((size_t)(p * 2048 + colg)) * 512;
        const unsigned short* WR = (const unsigned short*)Whv + ((size_t)(p * 2048 + colg)) * 512;
        union { uint4 u; bf16x8 v; } cvu;
        #pragma unroll
        for (int kk = 0; kk < 16; ++kk) {
            cvu.u = *(const uint4*)(WA + kk * 32 + quad * 8); wa[kk] = cvu.v;
            cvu.u = *(const uint4*)(WR + kk * 32 + quad * 8); wr[kk] = cvu.v;
        }
    }
    float bias;
    if (f32) bias = ((const float*)bxv)[p * 2048 + colg] + ((const float*)bhv)[p * 2048 + colg];
    else     bias = b2f(((const unsigned short*)bxv)[p * 2048 + colg])
                  + b2f(((const unsigned short*)bhv)[p * 2048 + colg]);

    // pointwise mapping: elems (b, n0), (b, n0+1); fp32 c-state in registers
    const int e0 = tid * 2;
    const int pbb = e0 >> 4;
    const int pn0 = e0 & 15;
    float cv[2];
    cv[0] = cws[p * 16384 + pbb * 512 + wt * 16 + pn0];
    cv[1] = cws[p * 16384 + pbb * 512 + wt * 16 + pn0 + 1];

    const unsigned short* xb = (const unsigned short*)xv;

    #define STAGE_X_BF16(T)                                                      \
        { _Pragma("unroll")                                                      \
          for (int j = 0; j < 8; ++j) {                                          \
              int L = j * 256 + tid;                                             \
              int rem = L & 127;                                                 \
              int row = ((rem >> 6) << 4) + (rem & 15);                          \
              int kcol = ((L >> 7) << 5) + (((rem >> 4) & 3) << 3);              \
              *(uint4*)(smem + (L << 4)) =                                       \
                  *(const uint4*)(xb + ((size_t)row * 512 + (T)) * 512 + kcol);  \
          } }

    #define STAGE_X_F32(T)                                                       \
        { _Pragma("unroll")                                                      \
          for (int j = 0; j < 8; ++j) {                                          \
              int L = j * 256 + tid;                                             \
              int rem = L & 127;                                                 \
              int row = ((rem >> 6) << 4) + (rem & 15);                          \
              int kcol = ((L >> 7) << 5) + (((rem >> 4) & 3) << 3);              \
              const float* xp = (const float*)xv + ((size_t)row * 512 + (T)) * 512 + kcol; \
              bf16x8 hi_, lo_;                                                   \
              split8(xp, hi_, lo_);                                              \
              *(bf16x8*)(smem + (L << 4)) = hi_;                                 \
              *(bf16x8*)(smem + 32768 + (L << 4)) = lo_;                         \
          } }

    // gather-then-scatter: 2 arrays (hi,lo) -> LDS regions DH/DL
    #define GATHER2(SH, SL, DH, DL)                                              \
        { u64 vH[16], vL[16];                                                    \
          _Pragma("unroll")                                                      \
          for (int j = 0; j < 8; ++j) {                                          \
              int L = j * 256 + tid;                                             \
              int rem = L & 127;                                                 \
              int row = ((rem >> 6) << 4) + (rem & 15);                          \
              int kcol = ((L >> 7) << 5) + (((rem >> 4) & 3) << 3);              \
              size_t hoff = (size_t)row * 512 + kcol;                            \
              vH[j*2] = gload8((SH) + hoff); vH[j*2+1] = gload8((SH) + hoff + 4);\
              vL[j*2] = gload8((SL) + hoff); vL[j*2+1] = gload8((SL) + hoff + 4);\
          }                                                                      \
          _Pragma("unroll")                                                      \
          for (int j = 0; j < 8; ++j) {                                          \
              int L = j * 256 + tid;                                             \
              u64* dH = (u64*)(smem + (DH) + (L << 4));                          \
              u64* dL = (u64*)(smem + (DL) + (L << 4));                          \
              dH[0] = vH[j*2]; dH[1] = vH[j*2+1];                                \
              dL[0] = vL[j*2]; dL[1] = vL[j*2+1];                                \
          } }

    // lane j polls flag of WG j; thresholds <=0 are skipped
    #define POLL(THR_E, THR_O)                                                   \
        { if (tid < 64) {                                                        \
              int thr_ = ((tid & 1) == 0) ? (THR_E) : (THR_O);                   \
              if (thr_ > 0) {                                                    \
                  while ((int)__hip_atomic_load(&flags[tid * 16],                \
                             __ATOMIC_RELAXED, __HIP_MEMORY_SCOPE_AGENT) < thr_) \
                      __builtin_amdgcn_s_sleep(1);                               \
              }                                                                  \
          }                                                                      \
          __syncthreads(); }

    // MFMA sub-phases (A tiles @0/32K, R tiles @64K/96K)
    #define MM_A_F32()                                                           \
        { _Pragma("unroll")                                                      \
          for (int kk = 0; kk < 16; ++kk) {                                      \
              bf16x8 Aha = *(const bf16x8*)(sl + kk * 2048);                     \
              bf16x8 Ahb = *(const bf16x8*)(sl + kk * 2048 + 1024);              \
              bf16x8 Ala = *(const bf16x8*)(sl + 32768 + kk * 2048);             \
              bf16x8 Alb = *(const bf16x8*)(sl + 32768 + kk * 2048 + 1024);      \
              acc0 = MFMA16(Aha, wa[kk], acc0);  acc1 = MFMA16(Ahb, wa[kk], acc1);   \
              acc0 = MFMA16(Aha, wal[kk], acc0); acc1 = MFMA16(Ahb, wal[kk], acc1);  \
              acc0 = MFMA16(Ala, wa[kk], acc0);  acc1 = MFMA16(Alb, wa[kk], acc1);   \
          } }

    #define MM_R_F32()                                                           \
        { _Pragma("unroll")                                                      \
          for (int kk = 0; kk < 16; ++kk) {                                      \
              bf16x8 Rha = *(const bf16x8*)(sl + 65536 + kk * 2048);             \
              bf16x8 Rhb = *(const bf16x8*)(sl + 65536 + kk * 2048 + 1024);      \
              bf16x8 Rla = *(const bf16x8*)(sl + 98304 + kk * 2048);             \
              bf16x8 Rlb = *(const bf16x8*)(sl + 98304 + kk * 2048 + 1024);      \
              acc0 = MFMA16(Rha, wr[kk], acc0);  acc1 = MFMA16(Rhb, wr[kk], acc1);   \
              acc0 = MFMA16(Rha, wrl[kk], acc0); acc1 = MFMA16(Rhb, wrl[kk], acc1);  \
              acc0 = MFMA16(Rla, wr[kk], acc0);  acc1 = MFMA16(Rlb, wr[kk], acc1);   \
          } }

    #define MM_A_BF16_P0()                                                       \
        { _Pragma("unroll")                                                      \
          for (int kk = 0; kk < 16; ++kk) {                                      \
              bf16x8 Aha = *(const bf16x8*)(sl + kk * 2048);                     \
              bf16x8 Ahb = *(const bf16x8*)(sl + kk * 2048 + 1024);              \
              acc0 = MFMA16(Aha, wa[kk], acc0);  acc1 = MFMA16(Ahb, wa[kk], acc1);   \
          } }

    #define MM_A_BF16_P1()                                                       \
        { _Pragma("unroll")                                                      \
          for (int kk = 0; kk < 16; ++kk) {                                      \
              bf16x8 Aha = *(const bf16x8*)(sl + kk * 2048);                     \
              bf16x8 Ahb = *(const bf16x8*)(sl + kk * 2048 + 1024);              \
              bf16x8 Ala = *(const bf16x8*)(sl + 32768 + kk * 2048);             \
              bf16x8 Alb = *(const bf16x8*)(sl + 32768 + kk * 2048 + 1024);      \
              acc0 = MFMA16(Aha, wa[kk], acc0);  acc1 = MFMA16(Ahb, wa[kk], acc1);   \
              acc0 = MFMA16(Ala, wa[kk], acc0);  acc1 = MFMA16(Alb, wa[kk], acc1);   \
          } }

    #define MM_R_BF16()                                                          \
        { _Pragma("unroll")                                                      \
          for (int kk = 0; kk < 16; ++kk) {                                      \
              bf16x8 Rha = *(const bf16x8*)(sl + 65536 + kk * 2048);             \
              bf16x8 Rhb = *(const bf16x8*)(sl + 65536 + kk * 2048 + 1024);      \
              bf16x8 Rla = *(const bf16x8*)(sl + 98304 + kk * 2048);             \
              bf16x8 Rlb = *(const bf16x8*)(sl + 98304 + kk * 2048 + 1024);      \
              acc0 = MFMA16(Rha, wr[kk], acc0);  acc1 = MFMA16(Rhb, wr[kk], acc1);   \
              acc0 = MFMA16(Rla, wr[kk], acc0);  acc1 = MFMA16(Rlb, wr[kk], acc1);   \
          } }

    // pre-stage x(0) for layer 0
    if (p == 0) {
        if (f32) { STAGE_X_F32(0) } else { STAGE_X_BF16(0) }
        __syncthreads();
    }

    for (int k = 0; k <= 512; ++k) {
        const bool doComp = (p == 0) ? (k < 512) : (k > 0);
        if (!doComp) {
            // p==1 at k==0, p==0 at k==512: just advance our flag
            if (tid == 0)
                __hip_atomic_store(&flags[blockIdx.x * 16], (unsigned)(k + 1),
                                   __ATOMIC_RELAXED, __HIP_MEMORY_SCOPE_AGENT);
            continue;
        }

        const char* sl = smem + (lane << 4);
        f32x4 acc0 = {bias, bias, bias, bias};
        f32x4 acc1 = {bias, bias, bias, bias};
        const int t = (p == 0) ? k : (k - 1);

        if (p == 0) {
            // ---- A-GEMM first (x tile prefetched; no peer dependency) ----
            if (f32) { MM_A_F32() } else { MM_A_BF16_P0() }
            // ---- wait: p0 peers >= k (data), p1 >= k-2 (slot-reuse flow control) ----
            POLL(k, k - 2)
            // ---- gather R = h0[k-1] (ring slot k&3) ----
            {
                const __hip_bfloat16* Rhi = h0hi + (size_t)(k & 3) * 16384;
                const __hip_bfloat16* Rlo = h0lo + (size_t)(k & 3) * 16384;
                GATHER2(Rhi, Rlo, 65536, 98304)
            }
            __syncthreads();
            if (f32) { MM_R_F32() } else { MM_R_BF16() }
        } else {
            // ---- A = h0[k-1] (ring slot k&3); p0 runs ahead so this is usually free ----
            POLL(k, 0)
            {
                const __hip_bfloat16* Ahi = h0hi + (size_t)(k & 3) * 16384;
                const __hip_bfloat16* Alo = h0lo + (size_t)(k & 3) * 16384;
                GATHER2(Ahi, Alo, 0, 32768)
            }
            __syncthreads();
            if (f32) { MM_A_F32() } else { MM_A_BF16_P1() }
            // ---- now wait for own-layer peers, then R = h1[k-2] (parity (k+1)&1) ----
            POLL(0, k)
            {
                const __hip_bfloat16* Rhi = h1hi + (size_t)((k + 1) & 1) * 16384;
                const __hip_bfloat16* Rlo = h1lo + (size_t)((k + 1) & 1) * 16384;
                GATHER2(Rhi, Rlo, 65536, 98304)
            }
            __syncthreads();
            if (f32) { MM_R_F32() } else { MM_R_BF16() }
        }

        // ---- gate transpose via gbuf ----
        #pragma unroll
        for (int r = 0; r < 4; ++r) {
            gbuf[(q * 32 + quad * 4 + r) * 17 + n16]      = acc0[r];
            gbuf[(q * 32 + 16 + quad * 4 + r) * 17 + n16] = acc1[r];
        }
        __syncthreads();

        // ---- pointwise epilogue ----
        __hip_bfloat16* Ohi = (p == 0) ? h0hi + (size_t)((k + 1) & 3) * 16384
                                       : h1hi + (size_t)(k & 1) * 16384;
        __hip_bfloat16* Olo = (p == 0) ? h0lo + (size_t)((k + 1) & 3) * 16384
                                       : h1lo + (size_t)(k & 1) * 16384;
        float rh[2], rc[2];
        #pragma unroll
        for (int j = 0; j < 2; ++j) {
            int n = pn0 + j;
            float ig = gbuf[(0 * 32 + pbb) * 17 + n];
            float fg = gbuf[(1 * 32 + pbb) * 17 + n];
            float gg = gbuf[(2 * 32 + pbb) * 17 + n];
            float og = gbuf[(3 * 32 + pbb) * 17 + n];
            float cnew = sigf(fg) * cv[j] + sigf(ig) * tanhf(gg);
            cv[j] = cnew;
            rc[j] = cnew;
            rh[j] = sigf(og) * tanhf(cnew);
        }
        unsigned phi = 0, plo = 0, pcn = 0;
        #pragma unroll
        for (int j = 0; j < 2; ++j) {
            unsigned short hu = f2u(rh[j]);
            unsigned short lu = f2u(rh[j] - b2f(hu));
            phi |= ((unsigned)hu) << (16 * j);
            plo |= ((unsigned)lu) << (16 * j);
            pcn |= ((unsigned)f2u(rc[j])) << (16 * j);
        }
        const int idx = pbb * 512 + wt * 16 + pn0;
        gstore4(Ohi + idx, phi);
        gstore4(Olo + idx, plo);

        // ---- publish ASAP: drain h stores, then flag; defer out stores ----
        __syncthreads();
        if (tid == 0)
            __hip_atomic_store(&flags[blockIdx.x * 16], (unsigned)(k + 1),
                               __ATOMIC_RELAXED, __HIP_MEMORY_SCOPE_AGENT);

        if (p == 1) {
            size_t oidx = ((size_t)pbb * 512 + t) * 512 + wt * 16 + pn0;
            if (f32) { outf[oidx] = rh[0]; outf[oidx + 1] = rh[1]; }
            else     { *(unsigned*)(outh + oidx) = phi; }
            if (k == 512) {
                if (f32) {
                    outf[HN_OFF + 16384 + idx] = rh[0]; outf[HN_OFF + 16385 + idx] = rh[1];
                    outf[CN_OFF + 16384 + idx] = rc[0]; outf[CN_OFF + 16385 + idx] = rc[1];
                } else {
                    *(unsigned*)(outh + HN_OFF + 16384 + idx) = phi;
                    *(unsigned*)(outh + CN_OFF + 16384 + idx) = pcn;
                }
            }
        } else if (k == 511) {
            if (f32) {
                outf[HN_OFF + idx] = rh[0]; outf[HN_OFF + idx + 1] = rh[1];
                outf[CN_OFF + idx] = rc[0]; outf[CN_OFF + idx + 1] = rc[1];
            } else {
                *(unsigned*)(outh + HN_OFF + idx) = phi;
                *(unsigned*)(outh + CN_OFF + idx) = pcn;
            }
        }

        // ---- prefetch next x tile into A region (overlaps peers' lag) ----
        if (p == 0) {
            if (k + 1 < 512) {
                if (f32) { STAGE_X_F32(k + 1) } else { STAGE_X_BF16(k + 1) }
            }
            __syncthreads();
        }
    }
}

extern "C" void kernel_launch(void* const* d_in, const int* in_sizes, int n_in,
                              void* d_out, int out_size, void* d_ws, size_t ws_size,
                              hipStream_t stream)
{
    const void* x  = d_in[0];
    const void* h0 = d_in[1];
    const void* c0 = d_in[2];
    const void* Wx = d_in[3];
    const void* bx = d_in[4];
    const void* Wh = d_in[5];
    const void* bh = d_in[6];

    char* ws = (char*)d_ws;                                    // total need: ~529 KB
    __hip_bfloat16* h0hi = (__hip_bfloat16*)(ws);              // [4][16384] bf16 (ring)
    __hip_bfloat16* h0lo = (__hip_bfloat16*)(ws + 131072);     // [4][16384]
    __hip_bfloat16* h1hi = (__hip_bfloat16*)(ws + 262144);     // [2][16384]
    __hip_bfloat16* h1lo = (__hip_bfloat16*)(ws + 327680);     // [2][16384]
    float*          cws  = (float*)(ws + 393216);              // [2][16384] f32
    unsigned*       flags = (unsigned*)(ws + 524288);          // 64 slots x 16 words
    unsigned*       dflag = (unsigned*)(ws + 528384);

    lstm_detect<<<1, 256, 0, stream>>>((const unsigned*)Wx, dflag, flags);
    lstm_init<<<64, 256, 0, stream>>>(h0, c0, h0hi, h0lo, h1hi, h1lo, cws, dflag);
    lstm_seq<<<64, 256, 0, stream>>>(x, Wx, bx, Wh, bh,
                                     h0hi, h0lo, h1hi, h1lo, cws, flags, dflag, d_out);
}